// Round 9
// baseline (167.016 us; speedup 1.0000x reference)
//
#include <hip/hip_runtime.h>

// Camera back-projection R9: R8 + NON-TEMPORAL output stores.
//
// R8 (49us kernel): LDS-staged tables, lanes = 16ix x 4iy (row-riding
// gathers), iz chunks of 32, 8 blocks/CU. Remaining gap vs the ~21us DRAM
// write floor traced to L2 thrash: the 16.8MB/XCD output write stream
// allocates through the same 4MB L2 that the XCD-local depth (1.8MB) and
// U/V tables need, evicting them continuously. R9 stores the output with
// __builtin_nontemporal_store (nt flag on global_store_dwordx4): write data
// bypasses L2 allocation, depth/tables stay resident, gathers stay hits.
//
// Numerics unchanged (absmax 0.0 every round): tables use exact IEEE '/' +
// rintf half-to-even in the reference's op order; epilogue
// max(fma(-128,|zc-d|,1),0) == 1-128*min(|zc-d|,1/128) exactly; d>0 test
// folded away (zc>=1.70 => d<=0 lands on the truncation branch anyway).

#define RES  128
#define IMG  480
#define MAXN 32
#define TS   36     // result tile row stride (floats)
#define US   136    // U slab row stride (ushorts)
#define VS   132    // V slab row stride (uints)

typedef float __attribute__((ext_vector_type(4))) f32x4;

__device__ unsigned short g_U[MAXN * RES * RES];  // [n][ix][iz]
__device__ unsigned       g_V[MAXN * RES * RES];  // [n][iy][iz]

__global__ __launch_bounds__(256) void cbp_tables(
    const float* __restrict__ fl, const float* __restrict__ cam_dist, int total)
{
    int t = blockIdx.x * 256 + threadIdx.x;
    if (t >= total) return;
    const int n = t >> 14;
    const int a = (t >> 7) & 127;   // ix for U, iy for V
    const int c = t & 127;          // iz for both
    const float flv = fl[n], cd = cam_dist[n];
    const float zc = cd - ((c + 0.5f) / 128.0f - 0.5f);
    {   // U (n, ix=a, iz=c) — same op order as reference
        const float x  = (a + 0.5f) / 128.0f - 0.5f;
        const float u  = (flv * x) / zc + 239.5f;            // exact IEEE div
        const int   ui = (int)fminf(fmaxf(rintf(u), 0.0f), 479.0f);
        const unsigned uok = (u >= 0.0f) && (u <= 479.0f);
        g_U[t] = (unsigned short)((ui << 2) | (uok << 15));
    }
    {   // V (n, iy=a, iz=c)
        const float y  = (a + 0.5f) / 128.0f - 0.5f;
        const float v  = (flv * y) / zc + 239.5f;            // exact IEEE div
        const int   vi = (int)fminf(fmaxf(rintf(v), 0.0f), 479.0f);
        const unsigned vok = (v >= 0.0f) && (v <= 479.0f) && (zc > 0.0f);
        g_V[t] = (unsigned)(vi * (IMG * 4)) | (vok << 31);   // vi*1920 < 2^20
    }
}

__global__ __launch_bounds__(256, 8) void cbp_main(
    const float* __restrict__ depth, const float* __restrict__ cam_dist,
    float* __restrict__ out, int N)
{
    __shared__ __align__(16) float          s_tile[64 * TS];  // 9216 B
    __shared__ __align__(16) unsigned short s_U[16 * US];     // 4352 B
    __shared__ __align__(16) unsigned       s_V[4 * VS];      // 2112 B
    __shared__ __align__(16) float          s_zc[RES];        //  512 B

    const int b = blockIdx.x;
    int n, r;
    if (N == 16) {                  // XCD-local: 2 images per XCD
        const int xcd = b & 7, i = b >> 3;
        n = xcd * 2 + (i >> 8);
        r = i & 255;
    } else { n = b >> 8; r = b & 255; }
    const int ixg = r & 7;          // 16-ix group (0..7)
    const int iyg = r >> 3;         // 4-iy group  (0..31)
    const int l   = threadIdx.x;
    const float cd = cam_dist[n];

    // ---- stage tables into LDS (coalesced, one-time) ----
    {   // U slab: 16 ix x 128 iz ushorts
        const int row = l >> 4, seg = l & 15;
        *(uint4*)&s_U[row * US + seg * 8] =
            *(const uint4*)&g_U[(n << 14) + ((ixg * 16 + row) << 7) + seg * 8];
        // V slab: 4 iy x 128 iz uints (512 consecutive)
        const unsigned* __restrict__ gv = &g_V[(n << 14) + ((iyg * 4) << 7)];
        s_V[((l >> 7)) * VS + (l & 127)]       = gv[l];
        s_V[((l + 256) >> 7) * VS + (l & 127)] = gv[l + 256];
        if (l < 128) s_zc[l] = cd - ((l + 0.5f) / 128.0f - 0.5f);
    }
    __syncthreads();

    const int ix_l = l & 15, iy_l = (l >> 4) & 3, w = l >> 6;
    const int trow = ix_l * 4 + iy_l;
    const char* __restrict__ dbase = (const char*)(depth + (size_t)n * (IMG * IMG));
    const size_t obase = ((size_t)((n << 7) + ixg * 16) << 7 | (iyg * 4)) << 7;

    for (int c = 0; c < 4; ++c) {
        // ---- compute: lanes = 16 ix x 4 iy, iz wave-uniform per instr ----
#pragma unroll
        for (int g = 0; g < 2; ++g) {
            const int jq  = w * 2 + g;          // iz quad within chunk (0..7)
            const int izc = c * 32 + jq * 4;    // global iz of quad
            const ushort4 pu4 = *(const ushort4*)&s_U[ix_l * US + izc];
            const uint4   pv4 = *(const uint4*)&s_V[iy_l * VS + izc];
            const float4  z4  = *(const float4*)&s_zc[izc];
            const unsigned pua[4] = {pu4.x, pu4.y, pu4.z, pu4.w};
            const unsigned pva[4] = {pv4.x, pv4.y, pv4.z, pv4.w};
            const float    zca[4] = {z4.x, z4.y, z4.z, z4.w};
            float4 rr; float* rp = &rr.x;
#pragma unroll
            for (int j = 0; j < 4; ++j) {
                const unsigned off = ((pua[j] & 0x7FFFu) + pva[j]) & 0xFFFFFu;
                const float d  = *(const float*)(dbase + off);   // L2-hot gather
                const bool ok  = (int)(pva[j] & (pua[j] << 16)) < 0;
                const float v  = fmaxf(fmaf(-128.0f, fabsf(zca[j] - d), 1.0f), 0.0f);
                rp[j] = ok ? v : 0.0f;
            }
            *(float4*)&s_tile[trow * TS + jq * 4] = rr;   // b128, bank floor
        }
        __syncthreads();

        // ---- store: non-temporal, wave instr = 8 full 128B lines ----
#pragma unroll
        for (int s = 0; s < 2; ++s) {
            const int f  = l + 256 * s;          // 0..511
            const int rw = f >> 3, q = f & 7;
            const f32x4 val = *(const f32x4*)&s_tile[rw * TS + q * 4];
            const int ix2 = rw >> 2, iy2 = rw & 3;
            __builtin_nontemporal_store(val,
                (f32x4*)&out[obase + ((size_t)ix2 << 14) + (iy2 << 7) + c * 32 + q * 4]);
        }
        __syncthreads();
    }
}

extern "C" void kernel_launch(void* const* d_in, const int* in_sizes, int n_in,
                              void* d_out, int out_size, void* d_ws, size_t ws_size,
                              hipStream_t stream) {
    const float* depth = (const float*)d_in[0];
    const float* fl    = (const float*)d_in[1];
    const float* cd    = (const float*)d_in[2];
    float* out         = (float*)d_out;

    const int N = in_sizes[1];                     // fl is (N,1)
    const int tab_total = N * RES * RES;
    cbp_tables<<<(tab_total + 255) / 256, 256, 0, stream>>>(fl, cd, tab_total);

    cbp_main<<<N * 256, 256, 0, stream>>>(depth, cd, out, N);
}

// Round 10
// 159.247 us; speedup vs baseline: 1.0488x; 1.0488x over previous
//
#include <hip/hip_runtime.h>

// Camera back-projection R10: R8 structure, tables folded in-block (1 dispatch).
//
// R8 (best, ~47us kernel / 160.3us bench): lanes = 16ix x 4iy (row-riding
// gathers, ~4-8 lines/instr), iz chunks of 32 transposed through a 9.2KB LDS
// tile at the b128 bank floor, 16.2KB LDS total -> 8 blocks/CU. R9's NT
// stores regressed (+7us) -> reverted. R10 removes the separate cbp_tables
// dispatch: each block computes its own U slab (16ix x 128iz) and V slab
// (4iy x 128iz) = 2560 exact IEEE divisions = 10/thread (~2us device-wide,
// overlapped across 8 resident blocks/CU), straight into LDS. Saves the
// serialized second dispatch + launch gap + 2.5MB global table round-trip.
//
// Numerics (absmax 0.0 every round): exact IEEE '/' + rintf half-to-even in
// the reference's op order; packing U = ui<<2|uok<<15 (ushort),
// V = vi*1920|vok<<31 (uint); gather byte offset = ((U&0x7FFF)+V)&0xFFFFF,
// valid = sign(V & U<<16); epilogue max(fma(-128,|zc-d|,1),0) ==
// 1-128*min(|zc-d|,1/128) exactly (pow2 scale); d>0 test folded away
// (zc>=1.70 puts d<=0 on the truncation branch regardless).

#define RES  128
#define IMG  480
#define TS   36     // result tile row stride (floats)
#define US   136    // U slab row stride (ushorts)
#define VS   132    // V slab row stride (uints)

__global__ __launch_bounds__(256, 8) void cbp_main(
    const float* __restrict__ depth, const float* __restrict__ fl,
    const float* __restrict__ cam_dist, float* __restrict__ out, int N)
{
    __shared__ __align__(16) float          s_tile[64 * TS];  // 9216 B
    __shared__ __align__(16) unsigned short s_U[16 * US];     // 4352 B
    __shared__ __align__(16) unsigned       s_V[4 * VS];      // 2112 B
    __shared__ __align__(16) float          s_zc[RES];        //  512 B

    const int b = blockIdx.x;
    int n, r;
    if (N == 16) {                  // XCD-local: 2 depth images per XCD's L2
        const int xcd = b & 7, i = b >> 3;
        n = xcd * 2 + (i >> 8);
        r = i & 255;
    } else { n = b >> 8; r = b & 255; }
    const int ixg = r & 7;          // 16-ix group (0..7)
    const int iyg = r >> 3;         // 4-iy group  (0..31)
    const int l   = threadIdx.x;
    const float flv = fl[n];
    const float cd  = cam_dist[n];

    // ---- in-block tables: 10 exact IEEE divisions per thread ----
    if (l < 128) s_zc[l] = cd - ((l + 0.5f) / 128.0f - 0.5f);
#pragma unroll
    for (int k = 0; k < 8; ++k) {   // U slab: 16 ix rows x 128 iz
        const int e   = l + 256 * k;
        const int row = e >> 7, izt = e & 127;
        const float zc = cd - ((izt + 0.5f) / 128.0f - 0.5f);
        const float x  = (ixg * 16 + row + 0.5f) / 128.0f - 0.5f;
        const float u  = (flv * x) / zc + 239.5f;            // exact IEEE div
        const int   ui = (int)fminf(fmaxf(rintf(u), 0.0f), 479.0f);
        const unsigned uok = (u >= 0.0f) && (u <= 479.0f);
        s_U[row * US + izt] = (unsigned short)((ui << 2) | (uok << 15));
    }
#pragma unroll
    for (int k = 0; k < 2; ++k) {   // V slab: 4 iy rows x 128 iz
        const int e   = l + 256 * k;
        const int iyt = e >> 7, izt = e & 127;
        const float zc = cd - ((izt + 0.5f) / 128.0f - 0.5f);
        const float y  = (iyg * 4 + iyt + 0.5f) / 128.0f - 0.5f;
        const float v  = (flv * y) / zc + 239.5f;            // exact IEEE div
        const int   vi = (int)fminf(fmaxf(rintf(v), 0.0f), 479.0f);
        const unsigned vok = (v >= 0.0f) && (v <= 479.0f) && (zc > 0.0f);
        s_V[iyt * VS + izt] = (unsigned)(vi * (IMG * 4)) | (vok << 31);
    }
    __syncthreads();

    const int ix_l = l & 15, iy_l = (l >> 4) & 3, w = l >> 6;
    const int trow = ix_l * 4 + iy_l;
    const char* __restrict__ dbase = (const char*)(depth + (size_t)n * (IMG * IMG));
    const size_t obase = ((size_t)((n << 7) + ixg * 16) << 7 | (iyg * 4)) << 7;

    for (int c = 0; c < 4; ++c) {
        // ---- compute: lanes = 16 ix x 4 iy, iz wave-uniform per instr ----
#pragma unroll
        for (int g = 0; g < 2; ++g) {
            const int jq  = w * 2 + g;          // iz quad within chunk (0..7)
            const int izc = c * 32 + jq * 4;    // global iz of quad
            const ushort4 pu4 = *(const ushort4*)&s_U[ix_l * US + izc];
            const uint4   pv4 = *(const uint4*)&s_V[iy_l * VS + izc];
            const float4  z4  = *(const float4*)&s_zc[izc];
            const unsigned pua[4] = {pu4.x, pu4.y, pu4.z, pu4.w};
            const unsigned pva[4] = {pv4.x, pv4.y, pv4.z, pv4.w};
            const float    zca[4] = {z4.x, z4.y, z4.z, z4.w};
            float4 rr; float* rp = &rr.x;
#pragma unroll
            for (int j = 0; j < 4; ++j) {
                const unsigned off = ((pua[j] & 0x7FFFu) + pva[j]) & 0xFFFFFu;
                const float d  = *(const float*)(dbase + off);   // cache-hot gather
                const bool ok  = (int)(pva[j] & (pua[j] << 16)) < 0;
                const float v  = fmaxf(fmaf(-128.0f, fabsf(zca[j] - d), 1.0f), 0.0f);
                rp[j] = ok ? v : 0.0f;
            }
            *(float4*)&s_tile[trow * TS + jq * 4] = rr;   // b128, bank floor
        }
        __syncthreads();

        // ---- store: 2 float4/thread; wave instr = 8 full 128B lines ----
#pragma unroll
        for (int s = 0; s < 2; ++s) {
            const int f  = l + 256 * s;          // 0..511
            const int rw = f >> 3, q = f & 7;
            const float4 val = *(const float4*)&s_tile[rw * TS + q * 4];
            const int ix2 = rw >> 2, iy2 = rw & 3;
            *(float4*)&out[obase + ((size_t)ix2 << 14) + (iy2 << 7) + c * 32 + q * 4] = val;
        }
        __syncthreads();
    }
}

extern "C" void kernel_launch(void* const* d_in, const int* in_sizes, int n_in,
                              void* d_out, int out_size, void* d_ws, size_t ws_size,
                              hipStream_t stream) {
    const float* depth = (const float*)d_in[0];
    const float* fl    = (const float*)d_in[1];
    const float* cd    = (const float*)d_in[2];
    float* out         = (float*)d_out;

    const int N = in_sizes[1];                     // fl is (N,1)
    cbp_main<<<N * 256, 256, 0, stream>>>(depth, fl, cd, out, N);
}

// Round 11
// 158.851 us; speedup vs baseline: 1.0514x; 1.0025x over previous
//
#include <hip/hip_runtime.h>

// Camera back-projection R11: R10 + software-pipelined gathers (regs) across
// the store phase.
//
// R10 (~48us kernel): in-block tables (LDS), lanes = 16ix x 4iy (row-riding
// gathers), 32-iz chunks transposed through a 9.2KB LDS tile, 8 blocks/CU.
// Remaining gap vs the ~22us DRAM-write floor attributed to gather latency
// serialized behind each post-store __syncthreads (vmcnt(0) drain): gathers
// for chunk c could not issue until chunk c-1's stores retired. R11 computes
// chunk c+1 into 8 registers/thread WHILE chunk c's tile streams to global:
//   compute(0); for c: [barrier; regs->tile; barrier; compute(c+1); store(c)]
// Gather latency is hidden behind the entire store phase instead of 2
// unrolled iterations. s_zc removed: zc = cd - fma(iz+0.5, 2^-7, -0.5) is
// bit-exact (all terms multiples of 2^-8, |.|<1 -> exact fp32), cutting LDS
// reads in the overlapped phase.
//
// Numerics (absmax 0.0 every round): exact IEEE '/' + rintf half-to-even in
// the reference's op order for tables; U = ui<<2|uok<<15 (ushort),
// V = vi*1920|vok<<31 (uint); offset = ((U&0x7FFF)+V)&0xFFFFF, valid =
// sign(V & U<<16); epilogue max(fma(-128,|zc-d|,1),0) ==
// 1-128*min(|zc-d|,1/128) exactly; d>0 folds into the truncation branch.

#define RES  128
#define IMG  480
#define TS   36     // result tile row stride (floats)
#define US   136    // U slab row stride (ushorts)
#define VS   132    // V slab row stride (uints)

template<int C>
__device__ __forceinline__ void compute_chunk(
    float* __restrict__ r,
    const unsigned short* __restrict__ sU,
    const unsigned* __restrict__ sV,
    const char* __restrict__ dbase,
    float cd, int ix_l, int iy_l, int w)
{
#pragma unroll
    for (int g = 0; g < 2; ++g) {
        const int jq  = w * 2 + g;           // iz quad slot (0..7)
        const int izc = C * 32 + jq * 4;     // global iz of quad
        const ushort4 pu4 = *(const ushort4*)&sU[ix_l * US + izc];
        const uint4   pv4 = *(const uint4*)&sV[iy_l * VS + izc];
        const unsigned pua[4] = {pu4.x, pu4.y, pu4.z, pu4.w};
        const unsigned pva[4] = {pv4.x, pv4.y, pv4.z, pv4.w};
#pragma unroll
        for (int j = 0; j < 4; ++j) {
            const int   iz = izc + j;
            const float z  = fmaf((float)iz + 0.5f, 0.0078125f, -0.5f); // exact
            const float zc = cd - z;
            const unsigned off = ((pua[j] & 0x7FFFu) + pva[j]) & 0xFFFFFu;
            const float d  = *(const float*)(dbase + off);   // cache-hot gather
            const bool ok  = (int)(pva[j] & (pua[j] << 16)) < 0;
            const float v  = fmaxf(fmaf(-128.0f, fabsf(zc - d), 1.0f), 0.0f);
            r[g * 4 + j] = ok ? v : 0.0f;
        }
    }
}

__global__ __launch_bounds__(256, 8) void cbp_main(
    const float* __restrict__ depth, const float* __restrict__ fl,
    const float* __restrict__ cam_dist, float* __restrict__ out, int N)
{
    __shared__ __align__(16) float          s_tile[64 * TS];  // 9216 B
    __shared__ __align__(16) unsigned short s_U[16 * US];     // 4352 B
    __shared__ __align__(16) unsigned       s_V[4 * VS];      // 2112 B

    const int b = blockIdx.x;
    int n, rblk;
    if (N == 16) {                  // XCD-local: 2 depth images per XCD's L2
        const int xcd = b & 7, i = b >> 3;
        n = xcd * 2 + (i >> 8);
        rblk = i & 255;
    } else { n = b >> 8; rblk = b & 255; }
    const int ixg = rblk & 7;       // 16-ix group (0..7)
    const int iyg = rblk >> 3;      // 4-iy group  (0..31)
    const int l   = threadIdx.x;
    const float flv = fl[n];
    const float cd  = cam_dist[n];

    // ---- in-block tables: 10 exact IEEE divisions per thread ----
#pragma unroll
    for (int k = 0; k < 8; ++k) {   // U slab: 16 ix rows x 128 iz
        const int e   = l + 256 * k;
        const int row = e >> 7, izt = e & 127;
        const float zc = cd - ((izt + 0.5f) / 128.0f - 0.5f);
        const float x  = (ixg * 16 + row + 0.5f) / 128.0f - 0.5f;
        const float u  = (flv * x) / zc + 239.5f;            // exact IEEE div
        const int   ui = (int)fminf(fmaxf(rintf(u), 0.0f), 479.0f);
        const unsigned uok = (u >= 0.0f) && (u <= 479.0f);
        s_U[row * US + izt] = (unsigned short)((ui << 2) | (uok << 15));
    }
#pragma unroll
    for (int k = 0; k < 2; ++k) {   // V slab: 4 iy rows x 128 iz
        const int e   = l + 256 * k;
        const int iyt = e >> 7, izt = e & 127;
        const float zc = cd - ((izt + 0.5f) / 128.0f - 0.5f);
        const float y  = (iyg * 4 + iyt + 0.5f) / 128.0f - 0.5f;
        const float v  = (flv * y) / zc + 239.5f;            // exact IEEE div
        const int   vi = (int)fminf(fmaxf(rintf(v), 0.0f), 479.0f);
        const unsigned vok = (v >= 0.0f) && (v <= 479.0f) && (zc > 0.0f);
        s_V[iyt * VS + izt] = (unsigned)(vi * (IMG * 4)) | (vok << 31);
    }
    __syncthreads();

    const int ix_l = l & 15, iy_l = (l >> 4) & 3, w = l >> 6;
    const int trow = ix_l * 4 + iy_l;
    const char* __restrict__ dbase = (const char*)(depth + (size_t)n * (IMG * IMG));
    const size_t obase = ((size_t)((n << 7) + ixg * 16) << 7 | (iyg * 4)) << 7;

    float r[8];                     // pipelined chunk results (2 float4)
    compute_chunk<0>(r, s_U, s_V, dbase, cd, ix_l, iy_l, w);

#pragma unroll
    for (int c = 0; c < 4; ++c) {
        __syncthreads();            // tile free (prev store-phase reads done)
        *(float4*)&s_tile[trow * TS + (w * 2) * 4]     = *(const float4*)&r[0];
        *(float4*)&s_tile[trow * TS + (w * 2 + 1) * 4] = *(const float4*)&r[4];
        __syncthreads();            // tile full

        // issue next chunk's gathers now; they overlap the store phase below
        if (c == 0) compute_chunk<1>(r, s_U, s_V, dbase, cd, ix_l, iy_l, w);
        else if (c == 1) compute_chunk<2>(r, s_U, s_V, dbase, cd, ix_l, iy_l, w);
        else if (c == 2) compute_chunk<3>(r, s_U, s_V, dbase, cd, ix_l, iy_l, w);

        // store: 2 float4/thread; wave instr = 8 full 128B lines
#pragma unroll
        for (int s = 0; s < 2; ++s) {
            const int f  = l + 256 * s;          // 0..511
            const int rw = f >> 3, q = f & 7;
            const float4 val = *(const float4*)&s_tile[rw * TS + q * 4];
            const int ix2 = rw >> 2, iy2 = rw & 3;
            *(float4*)&out[obase + ((size_t)ix2 << 14) + (iy2 << 7) + c * 32 + q * 4] = val;
        }
    }
}

extern "C" void kernel_launch(void* const* d_in, const int* in_sizes, int n_in,
                              void* d_out, int out_size, void* d_ws, size_t ws_size,
                              hipStream_t stream) {
    const float* depth = (const float*)d_in[0];
    const float* fl    = (const float*)d_in[1];
    const float* cd    = (const float*)d_in[2];
    float* out         = (float*)d_out;

    const int N = in_sizes[1];                     // fl is (N,1)
    cbp_main<<<N * 256, 256, 0, stream>>>(depth, fl, cd, out, N);
}